// Round 8
// baseline (426.991 us; speedup 1.0000x reference)
//
#include <hip/hip_runtime.h>
#include <stdint.h>

#define BATCH 256
#define M 512
#define N 512
#define K 128

typedef int int4v __attribute__((ext_vector_type(4)));

// R8 = STORE-PHASE ISOLATION. Launch: store_probe x2, real x1 (real kernel
// last -> correct output, absmax unaffected).
// Known so far (R6/R7): T_kernel=87us = stage 19us (at BW ceiling, R7) +
// compute+store 68us (vs ~46us ideal). The 23us slack is ALL in the
// compute+store region, which writes at an effective 3.9 TB/s while the
// harness fill proves pure writes sustain 6.5 TB/s. store_probe replays
// R0's epilogue store stream EXACTLY (same addresses, same burst order,
// scalar dword stores) with no loads/LDS/MFMA:
//   dur - 361.3 = 2 x T_store_pure.
//   ~41-46us -> mixing/rhythm starves the write pipe (fix: dense store
//               stream via wave specialization / epilogue pipelining).
//   ~60-68us -> single contiguous write stream per CU is the limit
//               (fix: interleave write regions per CU; else ceiling).
__global__ __launch_bounds__(512, 2) void store_probe(
    const float* __restrict__ alpha_p,
    float* __restrict__ O)
{
    const int tid  = threadIdx.x;
    const int bat  = blockIdx.x;
    const int lane = tid & 63;
    const int wave = tid >> 6;
    const int l15  = lane & 15;
    const int quad = lane >> 4;
    const int sn   = wave;

    const float alpha = *alpha_p;

    for (int sm = 0; sm < 8; ++sm) {
        float* Ob = O + ((size_t)bat * M + sm * 64 + quad * 4) * N + sn * 64 + l15;
#pragma unroll
        for (int i = 0; i < 4; ++i)
#pragma unroll
            for (int r = 0; r < 4; ++r) {
                float* rowp = Ob + (size_t)(i * 16 + r) * N;
#pragma unroll
                for (int j = 0; j < 4; ++j)
                    rowp[j * 16] = alpha * (float)(sm * 7 + i * 5 + r * 3 + j);
            }
    }
}

// Real kernel: byte-identical to R0 (best: 361.3us single-launch).
__global__ __launch_bounds__(512, 2) void bmm_s8s8_f32_kernel(
    const int* __restrict__ A32,       // [BATCH, M, K] int32 (values in [-128,127])
    const int* __restrict__ B32,       // [BATCH, N, K] int32
    const float* __restrict__ alpha_p, // scalar
    float* __restrict__ O)             // [BATCH, M, N] fp32
{
    __shared__ int8_t As[M * K]; // 64 KB
    __shared__ int8_t Bs[N * K]; // 64 KB

    const int tid = threadIdx.x;
    const int bat = blockIdx.x;

    const int* Ag = A32 + (size_t)bat * (M * K);
    const int* Bg = B32 + (size_t)bat * (N * K);

#pragma unroll 4
    for (int i = 0; i < 32; ++i) {
        const int g   = i * 512 + tid;   // dword-group 0..16383
        const int row = g >> 5;          // 32 groups per 128-int32 row
        const int kg  = g & 31;
        const int kc  = kg >> 2;         // 16B chunk 0..7
        const int sub = kg & 3;
        const int kcs = kc ^ (row & 7);

        int4v wa = *(const int4v*)(Ag + (size_t)g * 4);
        int4v wb = *(const int4v*)(Bg + (size_t)g * 4);
        const int pa = (wa.x & 0xff) | ((wa.y & 0xff) << 8) |
                       ((wa.z & 0xff) << 16) | (wa.w << 24);
        const int pb = (wb.x & 0xff) | ((wb.y & 0xff) << 8) |
                       ((wb.z & 0xff) << 16) | (wb.w << 24);
        *(int*)(As + row * 128 + kcs * 16 + sub * 4) = pa;
        *(int*)(Bs + row * 128 + kcs * 16 + sub * 4) = pb;
    }
    __syncthreads();

    const int lane = tid & 63;
    const int wave = tid >> 6;
    const int l15  = lane & 15;
    const int quad = lane >> 4;
    const int sn   = wave; // supertile column (n-offset sn*64)

    int4v bf[2][4];
#pragma unroll
    for (int ks = 0; ks < 2; ++ks)
#pragma unroll
        for (int j = 0; j < 4; ++j) {
            const int rb = sn * 64 + j * 16 + l15;
            const int kc = (ks * 4 + quad) ^ (rb & 7);
            bf[ks][j] = *(const int4v*)(Bs + rb * 128 + kc * 16);
        }

    const float alpha = *alpha_p;

    for (int sm = 0; sm < 8; ++sm) {
        int4v af[2][4];
#pragma unroll
        for (int ks = 0; ks < 2; ++ks)
#pragma unroll
            for (int i = 0; i < 4; ++i) {
                const int ra = sm * 64 + i * 16 + l15;
                const int kc = (ks * 4 + quad) ^ (ra & 7);
                af[ks][i] = *(const int4v*)(As + ra * 128 + kc * 16);
            }

        int4v acc[4][4];
#pragma unroll
        for (int i = 0; i < 4; ++i)
#pragma unroll
            for (int j = 0; j < 4; ++j)
                acc[i][j] = (int4v){0, 0, 0, 0};

#pragma unroll
        for (int ks = 0; ks < 2; ++ks)
#pragma unroll
            for (int i = 0; i < 4; ++i)
#pragma unroll
                for (int j = 0; j < 4; ++j)
                    acc[i][j] = __builtin_amdgcn_mfma_i32_16x16x64_i8(
                        af[ks][i], bf[ks][j], acc[i][j], 0, 0, 0);

        // C/D layout: col = lane&15 (n), row = quad*4 + reg (m).
        float* Ob = O + ((size_t)bat * M + sm * 64 + quad * 4) * N + sn * 64 + l15;
#pragma unroll
        for (int i = 0; i < 4; ++i)
#pragma unroll
            for (int r = 0; r < 4; ++r) {
                float* rowp = Ob + (size_t)(i * 16 + r) * N;
#pragma unroll
                for (int j = 0; j < 4; ++j)
                    rowp[j * 16] = alpha * (float)acc[i][j][r];
            }
    }
}

extern "C" void kernel_launch(void* const* d_in, const int* in_sizes, int n_in,
                              void* d_out, int out_size, void* d_ws, size_t ws_size,
                              hipStream_t stream) {
    const int*   a     = (const int*)d_in[0];
    const int*   b     = (const int*)d_in[1];
    const float* alpha = (const float*)d_in[2];
    float*       out   = (float*)d_out;

    dim3 grid(BATCH);
    dim3 block(512);
    // Probe x2 (garbage values, same store stream), then the real kernel.
    store_probe<<<grid, block, 0, stream>>>(alpha, out);
    store_probe<<<grid, block, 0, stream>>>(alpha, out);
    bmm_s8s8_f32_kernel<<<grid, block, 0, stream>>>(a, b, alpha, out);
}

// Round 9
// 363.236 us; speedup vs baseline: 1.1755x; 1.1755x over previous
//
#include <hip/hip_runtime.h>
#include <stdint.h>

#define BATCH 256
#define M 512
#define N 512
#define K 128

typedef int int4v __attribute__((ext_vector_type(4)));
typedef float float4v __attribute__((ext_vector_type(4)));

// R9: attack per-wave outstanding-store depth (the last coherent explanation
// of the 23us gap; see R8 post-mortem). Swapped-operand MFMA (R1's layout,
// harness-proven) -> each 16x16 tile's 4 acc regs = 4 consecutive n -> one
// CACHED global_store_dwordx4 per tile (16/supertile vs 64 scalar). Results
// live in DEDICATED double-banked registers (fout0/fout1, statically
// indexed, 128 VGPR): bank s's regs are untouched until supertile s+2, so
// stores stay in flight ~2 supertiles deep (32 insts x 1KB = 32KB/wave
// outstanding vs ~2-4KB with compiler-recycled temps). Stage/swizzle/bf
// hoist identical to R0. No NT (R1 showed NT+partial-line amplifies HBM).
__global__ __launch_bounds__(512, 2) void bmm_s8s8_f32_kernel(
    const int* __restrict__ A32,       // [BATCH, M, K] int32 (values in [-128,127])
    const int* __restrict__ B32,       // [BATCH, N, K] int32
    const float* __restrict__ alpha_p, // scalar
    float* __restrict__ O)             // [BATCH, M, N] fp32
{
    __shared__ int8_t As[M * K]; // 64 KB
    __shared__ int8_t Bs[N * K]; // 64 KB

    const int tid = threadIdx.x;
    const int bat = blockIdx.x;

    const int* Ag = A32 + (size_t)bat * (M * K);
    const int* Bg = B32 + (size_t)bat * (N * K);

    // ---- Stage + pack (identical to R0).
    // LDS layout: row-major [row][128] int8 with 16B-chunk XOR swizzle:
    //   byte addr = row*128 + (chunk ^ (row & 7))*16 + sub*4
#pragma unroll 4
    for (int i = 0; i < 32; ++i) {
        const int g   = i * 512 + tid;   // dword-group 0..16383
        const int row = g >> 5;          // 32 groups per 128-int32 row
        const int kg  = g & 31;
        const int kc  = kg >> 2;         // 16B chunk 0..7
        const int sub = kg & 3;
        const int kcs = kc ^ (row & 7);

        int4v wa = *(const int4v*)(Ag + (size_t)g * 4);
        int4v wb = *(const int4v*)(Bg + (size_t)g * 4);
        const int pa = (wa.x & 0xff) | ((wa.y & 0xff) << 8) |
                       ((wa.z & 0xff) << 16) | (wa.w << 24);
        const int pb = (wb.x & 0xff) | ((wb.y & 0xff) << 8) |
                       ((wb.z & 0xff) << 16) | (wb.w << 24);
        *(int*)(As + row * 128 + kcs * 16 + sub * 4) = pa;
        *(int*)(Bs + row * 128 + kcs * 16 + sub * 4) = pb;
    }
    __syncthreads();

    const int lane = tid & 63;
    const int wave = tid >> 6;
    const int l15  = lane & 15;
    const int quad = lane >> 4;
    const int sn   = wave; // supertile column (n-offset sn*64)

    // Hoist B fragments for this wave's column strip (identical to R0).
    int4v bf[2][4];
#pragma unroll
    for (int ks = 0; ks < 2; ++ks)
#pragma unroll
        for (int j = 0; j < 4; ++j) {
            const int rb = sn * 64 + j * 16 + l15;
            const int kc = (ks * 4 + quad) ^ (rb & 7);
            bf[ks][j] = *(const int4v*)(Bs + rb * 128 + kc * 16);
        }

    const float alpha = *alpha_p;

    // Two dedicated store-data banks, statically indexed (rule #20):
    // bank parity = sm&1. Stores from bank p stay in flight through the
    // next supertile; regs reused only at sm+2.
    float4v fout0[16];
    float4v fout1[16];

    // Per-supertile body. Swapped-operand MFMA: D = bf x af ->
    //   m_global = sm*64 + i*16 + l15
    //   n_global = sn*64 + j*16 + quad*4 + reg   (verified correct in R1)
#define PROCESS(SM_, FOUT_)                                                   \
    {                                                                         \
        const int sm_ = (SM_);                                                \
        int4v af[2][4];                                                       \
        _Pragma("unroll") for (int ks = 0; ks < 2; ++ks)                      \
            _Pragma("unroll") for (int i = 0; i < 4; ++i) {                   \
            const int ra = sm_ * 64 + i * 16 + l15;                           \
            const int kc = (ks * 4 + quad) ^ (ra & 7);                        \
            af[ks][i] = *(const int4v*)(As + ra * 128 + kc * 16);             \
        }                                                                     \
        _Pragma("unroll") for (int i = 0; i < 4; ++i)                         \
            _Pragma("unroll") for (int j = 0; j < 4; ++j) {                   \
            int4v acc = (int4v){0, 0, 0, 0};                                  \
            _Pragma("unroll") for (int ks = 0; ks < 2; ++ks)                  \
                acc = __builtin_amdgcn_mfma_i32_16x16x64_i8(                  \
                    bf[ks][j], af[ks][i], acc, 0, 0, 0);                      \
            float4v f;                                                        \
            f.x = alpha * (float)acc.x;                                       \
            f.y = alpha * (float)acc.y;                                       \
            f.z = alpha * (float)acc.z;                                       \
            f.w = alpha * (float)acc.w;                                       \
            FOUT_[i * 4 + j] = f;                                             \
        }                                                                     \
        float* Obase = O + ((size_t)bat * M + sm_ * 64 + l15) * N +           \
                       sn * 64 + quad * 4;                                    \
        _Pragma("unroll") for (int i = 0; i < 4; ++i)                         \
            _Pragma("unroll") for (int j = 0; j < 4; ++j) {                   \
            *(float4v*)(Obase + (size_t)(i * 16) * N + j * 16) =              \
                FOUT_[i * 4 + j];                                             \
        }                                                                     \
    }

#pragma unroll 1
    for (int smh = 0; smh < 4; ++smh) {
        PROCESS(2 * smh,     fout0)
        PROCESS(2 * smh + 1, fout1)
    }
#undef PROCESS
}

extern "C" void kernel_launch(void* const* d_in, const int* in_sizes, int n_in,
                              void* d_out, int out_size, void* d_ws, size_t ws_size,
                              hipStream_t stream) {
    const int*   a     = (const int*)d_in[0];
    const int*   b     = (const int*)d_in[1];
    const float* alpha = (const float*)d_in[2];
    float*       out   = (float*)d_out;

    dim3 grid(BATCH);
    dim3 block(512);
    bmm_s8s8_f32_kernel<<<grid, block, 0, stream>>>(a, b, alpha, out);
}